// Round 23
// baseline (139.779 us; speedup 1.0000x reference)
//
#include <hip/hip_runtime.h>
#include <math.h>

// B=8, G=2048, K=32, N=64.
// Algebraic: k_anp_x = mean(ff,K) exactly (e_x cancels); std/p/nrm branch
// dead; norm over G cancels the 2. Projection linear in 1/std => matmul on
// RAW diffs; inv applied in k2b only. knn read ONCE.
//
//  k2a : persistent pipeline (R22) with LDS-DELIVERY fix: lanes = 4 rows x
//        16 col-pairs, so each ds_read_b128 carries 4 distinct row-quads
//        (4x unique bytes; reads/row 8.5 -> 4.25). fB = 2 cols/lane =
//        136 VGPRs, pinned via asm (+v) against rematerialization.
//        Parity chains per column bit-identical to R22.
//  k1f : std from 1024 block partials
//  k2b : inv + sincos + K-reduce (A is L3-resident)
//  k3p/k3f : G-norm + finalize

constexpr int Gg = 2048;

typedef float v2f __attribute__((ext_vector_type(2)));

constexpr size_t PART_OFF = 0;       // k2a: 1024*2 doubles; later part2
constexpr size_t STD_OFF  = 32768;   // 1 float
constexpr size_t M_OFF    = 65536;   // 4 MiB
constexpr size_t ACC_OFF  = 65536 + 4194304;   // 32 MB raw acc

// ---------------- K2a: persistent pipelined fused kernel ----------------
__global__ __launch_bounds__(256, 3) void k2a_main(const float* __restrict__ knn,
                                                   const float* __restrict__ lc,
                                                   const float* __restrict__ fB,
                                                   double* __restrict__ part,
                                                   float* __restrict__ A)
{
    __shared__ float4 elds4[2][17][65];    // 34.5 KB double buffer (pad 65)

    const int tid = threadIdx.x;
    const int l   = tid & 63;
    const int w   = tid >> 6;
    // phase-1 ids (4 threads per row)
    const int p1row = tid >> 2;            // 0..63 (tile-local)
    const int sub   = tid & 3;
    const int p1g   = p1row >> 5;          // 0..1 (tile-local g)
    // phase-2 ids: 4 rows x 16 col-pairs per wave-read
    const int c2     = (l & 15) * 2;       // even column of the pair
    const int rowsel = l >> 4;             // 0..3 row within the set

    const size_t blk = blockIdx.x;         // block covers rows blk*512..+511

    // fB column pair resident: fbrA = col c2, fbrB = col c2+1 (136 VGPRs)
    v2f fbrA[34], fbrB[34];
    #pragma unroll
    for (int j = 0; j < 34; ++j) {
        fbrA[j] = (v2f){fB[(2 * j) * 32 + c2],     fB[(2 * j + 1) * 32 + c2]};
        fbrB[j] = (v2f){fB[(2 * j) * 32 + c2 + 1], fB[(2 * j + 1) * 32 + c2 + 1]};
    }
    #pragma unroll
    for (int j = 0; j < 34; ++j) {
        asm volatile("" : "+v"(fbrA[j]));  // pin: forbid rematerialization
        asm volatile("" : "+v"(fbrB[j]));
    }

    double sD = 0.0, s2D = 0.0;

    auto P1 = [&](int t, int bsel) {
        const float4* rowp = (const float4*)knn
            + ((size_t)blk * 512 + t * 64 + p1row) * 16 + sub * 4;
        const float4* lcp  = (const float4*)lc
            + ((size_t)blk * 16 + t * 2 + p1g) * 16 + sub * 4;
        float dotp = 0.0f;
        float kn0 = 0, kn1 = 0, kn2 = 0, ln0 = 0, ln1 = 0, ln2 = 0;
        float s0 = 0.f, s1 = 0.f, s2c = 0.f, s3 = 0.f;
        float q0 = 0.f, q1 = 0.f, q2c = 0.f, q3 = 0.f;
        #pragma unroll
        for (int j = 0; j < 4; ++j) {
            float4 qv = rowp[j];
            float4 lv = lcp[j];
            float e0 = qv.x - lv.x, e1 = qv.y - lv.y;
            float e2 = qv.z - lv.z, e3 = qv.w - lv.w;
            if (j == 0 && sub == 0) {
                kn0 = e0; kn1 = e1; kn2 = e2;
                ln0 = lv.x; ln1 = lv.y; ln2 = lv.z;
            }
            dotp = fmaf(e0, lv.x, dotp); dotp = fmaf(e1, lv.y, dotp);
            dotp = fmaf(e2, lv.z, dotp); dotp = fmaf(e3, lv.w, dotp);
            s0 += e0; s1 += e1; s2c += e2; s3 += e3;
            q0 = fmaf(e0, e0, q0); q1 = fmaf(e1, e1, q1);
            q2c = fmaf(e2, e2, q2c); q3 = fmaf(e3, e3, q3);
            elds4[bsel][sub * 4 + j][p1row] = make_float4(e0, e1, e2, e3);
        }
        float d1  = dotp + __shfl_xor(dotp, 1);
        float dot = d1 + __shfl_xor(d1, 2);
        if (sub == 0) {
            float a0 = kn0, a1 = kn1, a2 = kn2;
            float b0 = ln0, b1 = ln1, b2 = ln2;
            float t2;
            if (a0 < a1) { t2 = a0; a0 = a1; a1 = t2; }
            if (a1 < a2) { t2 = a1; a1 = a2; a2 = t2; }
            if (a0 < a1) { t2 = a0; a0 = a1; a1 = t2; }
            if (b0 < b1) { t2 = b0; b0 = b1; b1 = t2; }
            if (b1 < b2) { t2 = b1; b1 = b2; b2 = t2; }
            if (b0 < b1) { t2 = b0; b0 = b1; b1 = t2; }
            float cr0 = a1 * b2 - a2 * b1;
            float cr1 = a2 * b0 - a0 * b2;
            float cr2 = a0 * b1 - a1 * b0;
            elds4[bsel][16][p1row] = make_float4(cr0, cr1, cr2, dot);
        }
        sD  += (double)s0 + (double)s1 + (double)s2c + (double)s3;
        s2D += (double)q0 + (double)q1 + (double)q2c + (double)q3;
    };

    auto P2 = [&](int t, int bsel) {
        #pragma unroll
        for (int s = 0; s < 4; ++s) {
            const int r = w * 16 + s * 4 + rowsel;   // tile-local row
            v2f a0 = (v2f){0.f, 0.f}, a1 = (v2f){0.f, 0.f};
            v2f b0 = (v2f){0.f, 0.f}, b1 = (v2f){0.f, 0.f};
            #pragma unroll
            for (int kq = 0; kq < 17; ++kq) {
                float4 e4 = elds4[bsel][kq][r];      // 4 distinct addrs/wave
                a0 = __builtin_elementwise_fma((v2f){e4.x, e4.y}, fbrA[2 * kq],     a0);
                a1 = __builtin_elementwise_fma((v2f){e4.z, e4.w}, fbrA[2 * kq + 1], a1);
                b0 = __builtin_elementwise_fma((v2f){e4.x, e4.y}, fbrB[2 * kq],     b0);
                b1 = __builtin_elementwise_fma((v2f){e4.z, e4.w}, fbrB[2 * kq + 1], b1);
            }
            v2f fin = (v2f){(a0.x + a0.y) + (a1.x + a1.y),
                            (b0.x + b0.y) + (b1.x + b1.y)};
            *(v2f*)(A + ((size_t)blk * 512 + t * 64 + r) * 32 + c2) = fin;
        }
    };

    P1(0, 0);
    for (int t = 0; t < 8; ++t) {
        __syncthreads();                  // buf[t&1] published; WAR cleared
        if (t < 7) P1(t + 1, (t + 1) & 1);
        P2(t, t & 1);
    }

    // block s/s2 tree (alias the feature buffer)
    __syncthreads();
    double* shd = (double*)&elds4[0][0][0];
    shd[tid] = sD; shd[256 + tid] = s2D;
    __syncthreads();
    for (int off = 128; off > 0; off >>= 1) {
        if (tid < off) { shd[tid] += shd[tid + off]; shd[256 + tid] += shd[256 + tid + off]; }
        __syncthreads();
    }
    if (tid == 0) { part[blk * 2] = shd[0]; part[blk * 2 + 1] = shd[256]; }
}

// ---------------- K1f: std from 1024 partials ----------------
__global__ __launch_bounds__(256) void k1_final(const double* __restrict__ part,
                                                float* __restrict__ stdp)
{
    int tid = threadIdx.x;
    double s = 0.0, s2 = 0.0;
    for (int i = tid; i < 1024; i += 256) { s += part[2*i]; s2 += part[2*i+1]; }
    __shared__ double sh[512];
    sh[tid] = s; sh[256 + tid] = s2;
    __syncthreads();
    for (int off = 128; off > 0; off >>= 1) {
        if (tid < off) { sh[tid] += sh[tid + off]; sh[256 + tid] += sh[256 + tid + off]; }
        __syncthreads();
    }
    if (tid == 0) {
        double S = sh[0], S2 = sh[256];
        double Mn = 33554432.0;
        double var = (S2 - S * S / Mn) / (Mn - 1.0);
        stdp[0] = (float)sqrt(var);
    }
}

// ---------------- K2b: inv + sincos + K-reduce (L3-bound) ----------------
__global__ __launch_bounds__(256) void k2b_main(const float* __restrict__ A,
                                                const float* __restrict__ stdp,
                                                float* __restrict__ M)
{
    const int tid = threadIdx.x;
    const int g   = tid >> 5;           // 0..7
    const int c   = tid & 31;
    const float inv = 1.0f / (stdp[0] + 1e-5f);
    const float* Ab = A + ((size_t)blockIdx.x * 256 + g * 32) * 32 + c;
    float ssum = 0.0f, csum = 0.0f;
    #pragma unroll 4
    for (int k = 0; k < 32; ++k) {
        float p  = Ab[(size_t)k * 32] * inv;   // revolutions
        float rv = p - rintf(p);               // exact reduction
        ssum += __builtin_amdgcn_sinf(rv);
        csum += __builtin_amdgcn_cosf(rv);
    }
    const size_t mrow = (size_t)(blockIdx.x * 8 + g) * 64;
    M[mrow + c]      = ssum * (1.0f / 32.0f);
    M[mrow + 32 + c] = csum * (1.0f / 32.0f);
}

// ---------------- K3p: per-(b,gb) partial ssq over 128 g ----------------
__global__ __launch_bounds__(256) void k3_part(const float* __restrict__ M,
                                               float* __restrict__ part2)
{
    int blk = blockIdx.x;                 // b*16 + gb
    int b = blk >> 4, gb = blk & 15;
    int t = threadIdx.x;
    int c = t & 63, gs = t >> 6;          // 0..3
    const float* base = M + ((size_t)(b * Gg + gb * 128 + gs)) * 64 + c;
    float ss = 0.0f;
    #pragma unroll
    for (int i = 0; i < 32; ++i) {
        float v = base[(size_t)i * 256];
        ss = fmaf(v, v, ss);
    }
    __shared__ float sh[256];
    sh[t] = ss;
    __syncthreads();
    if (t < 64) part2[blk * 64 + t] = sh[t] + sh[t + 64] + sh[t + 128] + sh[t + 192];
}

// ---------------- K3f: finalize (folds the b-level reduce) ----------------
__global__ __launch_bounds__(256) void k3_final(const float* __restrict__ M,
                                                const float* __restrict__ lc,
                                                const float* __restrict__ part2,
                                                float* __restrict__ out)
{
    __shared__ float mt[64][65];
    __shared__ float lt[64][65];
    __shared__ float ir[64];
    __shared__ float iln[64];
    int tid = threadIdx.x;
    int b  = blockIdx.x >> 5;
    int g0 = (blockIdx.x & 31) * 64;
    if (tid < 64) {
        float s = 0.0f;
        #pragma unroll
        for (int gb = 0; gb < 16; ++gb) s += part2[(b * 16 + gb) * 64 + tid];
        ir[tid] = 1.0f / sqrtf(s);
    }
    const float* Mb = M  + ((size_t)(b * Gg + g0)) * 64;
    const float* Lb = lc + ((size_t)(b * Gg + g0)) * 64;
    #pragma unroll
    for (int i = 0; i < 4; ++i) {
        int f = i * 1024 + tid * 4;
        int r = f >> 6, col = f & 63;
        float4 mv = *(const float4*)(Mb + f);
        float4 lv = *(const float4*)(Lb + f);
        mt[r][col] = mv.x; mt[r][col+1] = mv.y; mt[r][col+2] = mv.z; mt[r][col+3] = mv.w;
        lt[r][col] = lv.x; lt[r][col+1] = lv.y; lt[r][col+2] = lv.z; lt[r][col+3] = lv.w;
    }
    __syncthreads();
    if (tid < 64) {
        float ss = 0.0f;
        #pragma unroll
        for (int c = 0; c < 64; ++c) { float v = lt[tid][c]; ss = fmaf(v, v, ss); }
        iln[tid] = 1.0f / sqrtf(ss);
    }
    __syncthreads();
    int gl = tid & 63;
    int c0 = tid >> 6;
    float il = iln[gl];
    int obase = (b * 128) * Gg + g0 + gl;
    #pragma unroll
    for (int i = 0; i < 16; ++i) {
        int c = c0 + i * 4;
        float lcl = lt[gl][c] * il;
        float x = mt[gl][c] * ir[c];
        float kl = 0.5f * x * (1.0f + erff(x * 0.70710678118654752f));
        out[obase + c * Gg]        = kl - lcl;   // line_element
        out[obase + (c + 64) * Gg] = lcl;        // lc_line
    }
}

extern "C" void kernel_launch(void* const* d_in, const int* in_sizes, int n_in,
                              void* d_out, int out_size, void* d_ws, size_t ws_size,
                              hipStream_t stream)
{
    (void)in_sizes; (void)n_in; (void)out_size; (void)ws_size;
    const float* lc  = (const float*)d_in[0];   // (8,2048,64)
    const float* knn = (const float*)d_in[1];   // (8,2048,32,64)
    const float* fB  = (const float*)d_in[2];   // (68,32)
    float* out = (float*)d_out;                 // (8,128,2048) f32
    char* ws = (char*)d_ws;
    double* part  = (double*)(ws + PART_OFF);
    float*  part2 = (float*)(ws + PART_OFF);
    float*  stdp  = (float*)(ws + STD_OFF);
    float*  M     = (float*)(ws + M_OFF);
    float*  A     = (float*)(ws + ACC_OFF);

    hipLaunchKernelGGL(k2a_main, dim3(1024), dim3(256), 0, stream,
                       knn, lc, fB, part, A);
    hipLaunchKernelGGL(k1_final, dim3(1), dim3(256), 0, stream, part, stdp);
    hipLaunchKernelGGL(k2b_main, dim3(2048), dim3(256), 0, stream, A, stdp, M);
    hipLaunchKernelGGL(k3_part, dim3(128), dim3(256), 0, stream, M, part2);
    hipLaunchKernelGGL(k3_final, dim3(256), dim3(256), 0, stream, M, lc, part2, out);
}

// Round 24
// 86.473 us; speedup vs baseline: 1.6165x; 1.6165x over previous
//
#include <hip/hip_runtime.h>
#include <math.h>

// B=8, G=2048, K=32, N=64.
// Algebraic: k_anp_x = mean(ff,K) exactly (e_x cancels); std/p/nrm branch
// dead; norm over G cancels the 2. Projection linear in 1/std => matmul on
// RAW diffs; inv applied in k2b only. knn read ONCE.
//
//  k2a : persistent pipeline with the LDS-DELIVERY fix (lanes = 4 rows x
//        16 col-pairs: each ds_read_b128 carries 4 distinct row-quads,
//        reads/row 8.5 -> 4.25). fB = 2 cols/lane = 136 VGPRs, pinned.
//        R23 spilled at (256,3) [170-reg budget]; now (256,2) [256 regs].
//  k1f : std from 1024 block partials
//  k2b : inv + sincos + K-reduce (A is L3-resident)
//  k3p/k3f : G-norm + finalize

constexpr int Gg = 2048;

typedef float v2f __attribute__((ext_vector_type(2)));

constexpr size_t PART_OFF = 0;       // k2a: 1024*2 doubles; later part2
constexpr size_t STD_OFF  = 32768;   // 1 float
constexpr size_t M_OFF    = 65536;   // 4 MiB
constexpr size_t ACC_OFF  = 65536 + 4194304;   // 32 MB raw acc

// ---------------- K2a: persistent pipelined fused kernel ----------------
__global__ __launch_bounds__(256, 2) void k2a_main(const float* __restrict__ knn,
                                                   const float* __restrict__ lc,
                                                   const float* __restrict__ fB,
                                                   double* __restrict__ part,
                                                   float* __restrict__ A)
{
    __shared__ float4 elds4[2][17][65];    // 34.5 KB double buffer (pad 65)

    const int tid = threadIdx.x;
    const int l   = tid & 63;
    const int w   = tid >> 6;
    // phase-1 ids (4 threads per row)
    const int p1row = tid >> 2;            // 0..63 (tile-local)
    const int sub   = tid & 3;
    const int p1g   = p1row >> 5;          // 0..1 (tile-local g)
    // phase-2 ids: 4 rows x 16 col-pairs per wave-read
    const int c2     = (l & 15) * 2;       // even column of the pair
    const int rowsel = l >> 4;             // 0..3 row within the set

    const size_t blk = blockIdx.x;         // block covers rows blk*512..+511

    // fB column pair resident: fbrA = col c2, fbrB = col c2+1 (136 VGPRs)
    v2f fbrA[34], fbrB[34];
    #pragma unroll
    for (int j = 0; j < 34; ++j) {
        fbrA[j] = (v2f){fB[(2 * j) * 32 + c2],     fB[(2 * j + 1) * 32 + c2]};
        fbrB[j] = (v2f){fB[(2 * j) * 32 + c2 + 1], fB[(2 * j + 1) * 32 + c2 + 1]};
    }
    #pragma unroll
    for (int j = 0; j < 34; ++j) {
        asm volatile("" : "+v"(fbrA[j]));  // pin: forbid rematerialization
        asm volatile("" : "+v"(fbrB[j]));
    }

    double sD = 0.0, s2D = 0.0;

    auto P1 = [&](int t, int bsel) {
        const float4* rowp = (const float4*)knn
            + ((size_t)blk * 512 + t * 64 + p1row) * 16 + sub * 4;
        const float4* lcp  = (const float4*)lc
            + ((size_t)blk * 16 + t * 2 + p1g) * 16 + sub * 4;
        float dotp = 0.0f;
        float kn0 = 0, kn1 = 0, kn2 = 0, ln0 = 0, ln1 = 0, ln2 = 0;
        float s0 = 0.f, s1 = 0.f, s2c = 0.f, s3 = 0.f;
        float q0 = 0.f, q1 = 0.f, q2c = 0.f, q3 = 0.f;
        #pragma unroll
        for (int j = 0; j < 4; ++j) {
            float4 qv = rowp[j];
            float4 lv = lcp[j];
            float e0 = qv.x - lv.x, e1 = qv.y - lv.y;
            float e2 = qv.z - lv.z, e3 = qv.w - lv.w;
            if (j == 0 && sub == 0) {
                kn0 = e0; kn1 = e1; kn2 = e2;
                ln0 = lv.x; ln1 = lv.y; ln2 = lv.z;
            }
            dotp = fmaf(e0, lv.x, dotp); dotp = fmaf(e1, lv.y, dotp);
            dotp = fmaf(e2, lv.z, dotp); dotp = fmaf(e3, lv.w, dotp);
            s0 += e0; s1 += e1; s2c += e2; s3 += e3;
            q0 = fmaf(e0, e0, q0); q1 = fmaf(e1, e1, q1);
            q2c = fmaf(e2, e2, q2c); q3 = fmaf(e3, e3, q3);
            elds4[bsel][sub * 4 + j][p1row] = make_float4(e0, e1, e2, e3);
        }
        float d1  = dotp + __shfl_xor(dotp, 1);
        float dot = d1 + __shfl_xor(d1, 2);
        if (sub == 0) {
            float a0 = kn0, a1 = kn1, a2 = kn2;
            float b0 = ln0, b1 = ln1, b2 = ln2;
            float t2;
            if (a0 < a1) { t2 = a0; a0 = a1; a1 = t2; }
            if (a1 < a2) { t2 = a1; a1 = a2; a2 = t2; }
            if (a0 < a1) { t2 = a0; a0 = a1; a1 = t2; }
            if (b0 < b1) { t2 = b0; b0 = b1; b1 = t2; }
            if (b1 < b2) { t2 = b1; b1 = b2; b2 = t2; }
            if (b0 < b1) { t2 = b0; b0 = b1; b1 = t2; }
            float cr0 = a1 * b2 - a2 * b1;
            float cr1 = a2 * b0 - a0 * b2;
            float cr2 = a0 * b1 - a1 * b0;
            elds4[bsel][16][p1row] = make_float4(cr0, cr1, cr2, dot);
        }
        sD  += (double)s0 + (double)s1 + (double)s2c + (double)s3;
        s2D += (double)q0 + (double)q1 + (double)q2c + (double)q3;
    };

    auto P2 = [&](int t, int bsel) {
        #pragma unroll
        for (int s = 0; s < 4; ++s) {
            const int r = w * 16 + s * 4 + rowsel;   // tile-local row
            v2f a0 = (v2f){0.f, 0.f}, a1 = (v2f){0.f, 0.f};
            v2f b0 = (v2f){0.f, 0.f}, b1 = (v2f){0.f, 0.f};
            #pragma unroll
            for (int kq = 0; kq < 17; ++kq) {
                float4 e4 = elds4[bsel][kq][r];      // 4 distinct addrs/wave
                a0 = __builtin_elementwise_fma((v2f){e4.x, e4.y}, fbrA[2 * kq],     a0);
                a1 = __builtin_elementwise_fma((v2f){e4.z, e4.w}, fbrA[2 * kq + 1], a1);
                b0 = __builtin_elementwise_fma((v2f){e4.x, e4.y}, fbrB[2 * kq],     b0);
                b1 = __builtin_elementwise_fma((v2f){e4.z, e4.w}, fbrB[2 * kq + 1], b1);
            }
            v2f fin = (v2f){(a0.x + a0.y) + (a1.x + a1.y),
                            (b0.x + b0.y) + (b1.x + b1.y)};
            *(v2f*)(A + ((size_t)blk * 512 + t * 64 + r) * 32 + c2) = fin;
        }
    };

    P1(0, 0);
    for (int t = 0; t < 8; ++t) {
        __syncthreads();                  // buf[t&1] published; WAR cleared
        if (t < 7) P1(t + 1, (t + 1) & 1);
        P2(t, t & 1);
    }

    // block s/s2 tree (alias the feature buffer)
    __syncthreads();
    double* shd = (double*)&elds4[0][0][0];
    shd[tid] = sD; shd[256 + tid] = s2D;
    __syncthreads();
    for (int off = 128; off > 0; off >>= 1) {
        if (tid < off) { shd[tid] += shd[tid + off]; shd[256 + tid] += shd[256 + tid + off]; }
        __syncthreads();
    }
    if (tid == 0) { part[blk * 2] = shd[0]; part[blk * 2 + 1] = shd[256]; }
}

// ---------------- K1f: std from 1024 partials ----------------
__global__ __launch_bounds__(256) void k1_final(const double* __restrict__ part,
                                                float* __restrict__ stdp)
{
    int tid = threadIdx.x;
    double s = 0.0, s2 = 0.0;
    for (int i = tid; i < 1024; i += 256) { s += part[2*i]; s2 += part[2*i+1]; }
    __shared__ double sh[512];
    sh[tid] = s; sh[256 + tid] = s2;
    __syncthreads();
    for (int off = 128; off > 0; off >>= 1) {
        if (tid < off) { sh[tid] += sh[tid + off]; sh[256 + tid] += sh[256 + tid + off]; }
        __syncthreads();
    }
    if (tid == 0) {
        double S = sh[0], S2 = sh[256];
        double Mn = 33554432.0;
        double var = (S2 - S * S / Mn) / (Mn - 1.0);
        stdp[0] = (float)sqrt(var);
    }
}

// ---------------- K2b: inv + sincos + K-reduce (L3-bound) ----------------
__global__ __launch_bounds__(256) void k2b_main(const float* __restrict__ A,
                                                const float* __restrict__ stdp,
                                                float* __restrict__ M)
{
    const int tid = threadIdx.x;
    const int g   = tid >> 5;           // 0..7
    const int c   = tid & 31;
    const float inv = 1.0f / (stdp[0] + 1e-5f);
    const float* Ab = A + ((size_t)blockIdx.x * 256 + g * 32) * 32 + c;
    float ssum = 0.0f, csum = 0.0f;
    #pragma unroll 4
    for (int k = 0; k < 32; ++k) {
        float p  = Ab[(size_t)k * 32] * inv;   // revolutions
        float rv = p - rintf(p);               // exact reduction
        ssum += __builtin_amdgcn_sinf(rv);
        csum += __builtin_amdgcn_cosf(rv);
    }
    const size_t mrow = (size_t)(blockIdx.x * 8 + g) * 64;
    M[mrow + c]      = ssum * (1.0f / 32.0f);
    M[mrow + 32 + c] = csum * (1.0f / 32.0f);
}

// ---------------- K3p: per-(b,gb) partial ssq over 128 g ----------------
__global__ __launch_bounds__(256) void k3_part(const float* __restrict__ M,
                                               float* __restrict__ part2)
{
    int blk = blockIdx.x;                 // b*16 + gb
    int b = blk >> 4, gb = blk & 15;
    int t = threadIdx.x;
    int c = t & 63, gs = t >> 6;          // 0..3
    const float* base = M + ((size_t)(b * Gg + gb * 128 + gs)) * 64 + c;
    float ss = 0.0f;
    #pragma unroll
    for (int i = 0; i < 32; ++i) {
        float v = base[(size_t)i * 256];
        ss = fmaf(v, v, ss);
    }
    __shared__ float sh[256];
    sh[t] = ss;
    __syncthreads();
    if (t < 64) part2[blk * 64 + t] = sh[t] + sh[t + 64] + sh[t + 128] + sh[t + 192];
}

// ---------------- K3f: finalize (folds the b-level reduce) ----------------
__global__ __launch_bounds__(256) void k3_final(const float* __restrict__ M,
                                                const float* __restrict__ lc,
                                                const float* __restrict__ part2,
                                                float* __restrict__ out)
{
    __shared__ float mt[64][65];
    __shared__ float lt[64][65];
    __shared__ float ir[64];
    __shared__ float iln[64];
    int tid = threadIdx.x;
    int b  = blockIdx.x >> 5;
    int g0 = (blockIdx.x & 31) * 64;
    if (tid < 64) {
        float s = 0.0f;
        #pragma unroll
        for (int gb = 0; gb < 16; ++gb) s += part2[(b * 16 + gb) * 64 + tid];
        ir[tid] = 1.0f / sqrtf(s);
    }
    const float* Mb = M  + ((size_t)(b * Gg + g0)) * 64;
    const float* Lb = lc + ((size_t)(b * Gg + g0)) * 64;
    #pragma unroll
    for (int i = 0; i < 4; ++i) {
        int f = i * 1024 + tid * 4;
        int r = f >> 6, col = f & 63;
        float4 mv = *(const float4*)(Mb + f);
        float4 lv = *(const float4*)(Lb + f);
        mt[r][col] = mv.x; mt[r][col+1] = mv.y; mt[r][col+2] = mv.z; mt[r][col+3] = mv.w;
        lt[r][col] = lv.x; lt[r][col+1] = lv.y; lt[r][col+2] = lv.z; lt[r][col+3] = lv.w;
    }
    __syncthreads();
    if (tid < 64) {
        float ss = 0.0f;
        #pragma unroll
        for (int c = 0; c < 64; ++c) { float v = lt[tid][c]; ss = fmaf(v, v, ss); }
        iln[tid] = 1.0f / sqrtf(ss);
    }
    __syncthreads();
    int gl = tid & 63;
    int c0 = tid >> 6;
    float il = iln[gl];
    int obase = (b * 128) * Gg + g0 + gl;
    #pragma unroll
    for (int i = 0; i < 16; ++i) {
        int c = c0 + i * 4;
        float lcl = lt[gl][c] * il;
        float x = mt[gl][c] * ir[c];
        float kl = 0.5f * x * (1.0f + erff(x * 0.70710678118654752f));
        out[obase + c * Gg]        = kl - lcl;   // line_element
        out[obase + (c + 64) * Gg] = lcl;        // lc_line
    }
}

extern "C" void kernel_launch(void* const* d_in, const int* in_sizes, int n_in,
                              void* d_out, int out_size, void* d_ws, size_t ws_size,
                              hipStream_t stream)
{
    (void)in_sizes; (void)n_in; (void)out_size; (void)ws_size;
    const float* lc  = (const float*)d_in[0];   // (8,2048,64)
    const float* knn = (const float*)d_in[1];   // (8,2048,32,64)
    const float* fB  = (const float*)d_in[2];   // (68,32)
    float* out = (float*)d_out;                 // (8,128,2048) f32
    char* ws = (char*)d_ws;
    double* part  = (double*)(ws + PART_OFF);
    float*  part2 = (float*)(ws + PART_OFF);
    float*  stdp  = (float*)(ws + STD_OFF);
    float*  M     = (float*)(ws + M_OFF);
    float*  A     = (float*)(ws + ACC_OFF);

    hipLaunchKernelGGL(k2a_main, dim3(1024), dim3(256), 0, stream,
                       knn, lc, fB, part, A);
    hipLaunchKernelGGL(k1_final, dim3(1), dim3(256), 0, stream, part, stdp);
    hipLaunchKernelGGL(k2b_main, dim3(2048), dim3(256), 0, stream, A, stdp, M);
    hipLaunchKernelGGL(k3_part, dim3(128), dim3(256), 0, stream, M, part2);
    hipLaunchKernelGGL(k3_final, dim3(256), dim3(256), 0, stream, M, lc, part2, out);
}

// Round 26
// 83.709 us; speedup vs baseline: 1.6698x; 1.0330x over previous
//
#include <hip/hip_runtime.h>
#include <math.h>

// B=8, G=2048, K=32, N=64.
// Algebraic: k_anp_x = mean(ff,K) exactly (e_x cancels); std/p/nrm branch
// dead; norm over G cancels the 2. Projection linear in 1/std => matmul on
// RAW diffs; inv applied after the global std is known. knn read ONCE.
//
//  k2a : R22 persistent pipeline (64-row tiles, 34.5KB LDS, 4 blocks/CU)
//        + setprio(1) around P2's pk block (T5).
//  k1f : std from 1024 block partials
//  k2bp: inv + sincos + K-reduce -> M, fused with per-block ssq partial
//        (LDS tree + 64 atomicAdd into part2)  [was k2b + k3p]
//  k3f : finalize (sums part2 over gb, gelu, output)

constexpr int Gg = 2048;

typedef float v2f __attribute__((ext_vector_type(2)));

constexpr size_t PART_OFF = 0;       // k2a: 1024*2 dbl (16KB); later part2 (32KB)
constexpr size_t STD_OFF  = 32768;   // 1 float
constexpr size_t M_OFF    = 65536;   // 4 MiB
constexpr size_t ACC_OFF  = 65536 + 4194304;   // 32 MB raw acc

// ---------------- K2a: persistent pipelined fused kernel ----------------
__global__ __launch_bounds__(256, 4) void k2a_main(const float* __restrict__ knn,
                                                   const float* __restrict__ lc,
                                                   const float* __restrict__ fB,
                                                   double* __restrict__ part,
                                                   float* __restrict__ A)
{
    __shared__ float4 elds4[2][17][65];    // 34.5 KB double buffer (pad 65)

    const int tid = threadIdx.x;
    const int l   = tid & 63;
    const int w   = tid >> 6;
    // phase-1 ids (4 threads per row)
    const int p1row = tid >> 2;            // 0..63 (tile-local)
    const int sub   = tid & 3;
    const int p1g   = p1row >> 5;          // 0..1 (tile-local g)
    // phase-2 ids: wave w rows w*16 + lh*8 .. +8
    const int c     = l & 31;
    const int lh    = l >> 5;
    const int rbp2  = w * 16 + lh * 8;     // tile-local row base

    const size_t blk = blockIdx.x;         // block covers rows blk*512..+511

    // fB column pairs
    v2f fbr2[34];
    #pragma unroll
    for (int j = 0; j < 34; ++j)
        fbr2[j] = (v2f){fB[(2 * j) * 32 + c], fB[(2 * j + 1) * 32 + c]};

    double sD = 0.0, s2D = 0.0;

    auto P1 = [&](int t, int bsel) {
        const float4* rowp = (const float4*)knn
            + ((size_t)blk * 512 + t * 64 + p1row) * 16 + sub * 4;
        const float4* lcp  = (const float4*)lc
            + ((size_t)blk * 16 + t * 2 + p1g) * 16 + sub * 4;
        float dotp = 0.0f;
        float kn0 = 0, kn1 = 0, kn2 = 0, ln0 = 0, ln1 = 0, ln2 = 0;
        float s0 = 0.f, s1 = 0.f, s2c = 0.f, s3 = 0.f;
        float q0 = 0.f, q1 = 0.f, q2c = 0.f, q3 = 0.f;
        #pragma unroll
        for (int j = 0; j < 4; ++j) {
            float4 qv = rowp[j];
            float4 lv = lcp[j];
            float e0 = qv.x - lv.x, e1 = qv.y - lv.y;
            float e2 = qv.z - lv.z, e3 = qv.w - lv.w;
            if (j == 0 && sub == 0) {
                kn0 = e0; kn1 = e1; kn2 = e2;
                ln0 = lv.x; ln1 = lv.y; ln2 = lv.z;
            }
            dotp = fmaf(e0, lv.x, dotp); dotp = fmaf(e1, lv.y, dotp);
            dotp = fmaf(e2, lv.z, dotp); dotp = fmaf(e3, lv.w, dotp);
            s0 += e0; s1 += e1; s2c += e2; s3 += e3;
            q0 = fmaf(e0, e0, q0); q1 = fmaf(e1, e1, q1);
            q2c = fmaf(e2, e2, q2c); q3 = fmaf(e3, e3, q3);
            elds4[bsel][sub * 4 + j][p1row] = make_float4(e0, e1, e2, e3);
        }
        float d1  = dotp + __shfl_xor(dotp, 1);
        float dot = d1 + __shfl_xor(d1, 2);
        if (sub == 0) {
            float a0 = kn0, a1 = kn1, a2 = kn2;
            float b0 = ln0, b1 = ln1, b2 = ln2;
            float t2;
            if (a0 < a1) { t2 = a0; a0 = a1; a1 = t2; }
            if (a1 < a2) { t2 = a1; a1 = a2; a2 = t2; }
            if (a0 < a1) { t2 = a0; a0 = a1; a1 = t2; }
            if (b0 < b1) { t2 = b0; b0 = b1; b1 = t2; }
            if (b1 < b2) { t2 = b1; b1 = b2; b2 = t2; }
            if (b0 < b1) { t2 = b0; b0 = b1; b1 = t2; }
            float cr0 = a1 * b2 - a2 * b1;
            float cr1 = a2 * b0 - a0 * b2;
            float cr2 = a0 * b1 - a1 * b0;
            elds4[bsel][16][p1row] = make_float4(cr0, cr1, cr2, dot);
        }
        sD  += (double)s0 + (double)s1 + (double)s2c + (double)s3;
        s2D += (double)q0 + (double)q1 + (double)q2c + (double)q3;
    };

    auto P2 = [&](int t, int bsel) {
        float* Ab = A + ((size_t)blk * 512 + t * 64 + rbp2) * 32 + c;
        __builtin_amdgcn_s_setprio(1);
        #pragma unroll
        for (int jj = 0; jj < 4; ++jj) {
            const int r0 = rbp2 + 2 * jj;
            const int r1 = r0 + 1;
            v2f aA0 = (v2f){0.f, 0.f}, aA1 = (v2f){0.f, 0.f};
            v2f aB0 = (v2f){0.f, 0.f}, aB1 = (v2f){0.f, 0.f};
            #pragma unroll
            for (int kq = 0; kq < 17; ++kq) {
                float4 eA = elds4[bsel][kq][r0];
                float4 eB = elds4[bsel][kq][r1];
                aA0 = __builtin_elementwise_fma((v2f){eA.x, eA.y}, fbr2[2 * kq],     aA0);
                aA1 = __builtin_elementwise_fma((v2f){eA.z, eA.w}, fbr2[2 * kq + 1], aA1);
                aB0 = __builtin_elementwise_fma((v2f){eB.x, eB.y}, fbr2[2 * kq],     aB0);
                aB1 = __builtin_elementwise_fma((v2f){eB.z, eB.w}, fbr2[2 * kq + 1], aB1);
            }
            Ab[(size_t)(2 * jj) * 32]     = (aA0.x + aA0.y) + (aA1.x + aA1.y);
            Ab[(size_t)(2 * jj + 1) * 32] = (aB0.x + aB0.y) + (aB1.x + aB1.y);
        }
        __builtin_amdgcn_s_setprio(0);
    };

    P1(0, 0);
    for (int t = 0; t < 8; ++t) {
        __syncthreads();                  // buf[t&1] published; WAR cleared
        if (t < 7) P1(t + 1, (t + 1) & 1);
        P2(t, t & 1);
    }

    // block s/s2 tree (alias the feature buffer)
    __syncthreads();
    double* shd = (double*)&elds4[0][0][0];
    shd[tid] = sD; shd[256 + tid] = s2D;
    __syncthreads();
    for (int off = 128; off > 0; off >>= 1) {
        if (tid < off) { shd[tid] += shd[tid + off]; shd[256 + tid] += shd[256 + tid + off]; }
        __syncthreads();
    }
    if (tid == 0) { part[blk * 2] = shd[0]; part[blk * 2 + 1] = shd[256]; }
}

// ---------------- K1f: std from 1024 partials ----------------
__global__ __launch_bounds__(256) void k1_final(const double* __restrict__ part,
                                                float* __restrict__ stdp)
{
    int tid = threadIdx.x;
    double s = 0.0, s2 = 0.0;
    for (int i = tid; i < 1024; i += 256) { s += part[2*i]; s2 += part[2*i+1]; }
    __shared__ double sh[512];
    sh[tid] = s; sh[256 + tid] = s2;
    __syncthreads();
    for (int off = 128; off > 0; off >>= 1) {
        if (tid < off) { sh[tid] += sh[tid + off]; sh[256 + tid] += sh[256 + tid + off]; }
        __syncthreads();
    }
    if (tid == 0) {
        double S = sh[0], S2 = sh[256];
        double Mn = 33554432.0;
        double var = (S2 - S * S / Mn) / (Mn - 1.0);
        stdp[0] = (float)sqrt(var);
    }
}

// ---------------- K2bp: inv+sincos+K-reduce -> M, + ssq partial ----------------
__global__ __launch_bounds__(256) void k2bp_main(const float* __restrict__ A,
                                                 const float* __restrict__ stdp,
                                                 float* __restrict__ M,
                                                 float* __restrict__ part2)
{
    __shared__ float acc2d[8][64];
    const int tid = threadIdx.x;
    const int g   = tid >> 5;           // 0..7
    const int c   = tid & 31;
    const float inv = 1.0f / (stdp[0] + 1e-5f);
    const float* Ab = A + ((size_t)blockIdx.x * 256 + g * 32) * 32 + c;
    float ssum = 0.0f, csum = 0.0f;
    #pragma unroll 4
    for (int k = 0; k < 32; ++k) {
        float p  = Ab[(size_t)k * 32] * inv;   // revolutions
        float rv = p - rintf(p);               // exact reduction
        ssum += __builtin_amdgcn_sinf(rv);
        csum += __builtin_amdgcn_cosf(rv);
    }
    float ms = ssum * (1.0f / 32.0f);
    float mc = csum * (1.0f / 32.0f);
    const size_t mrow = (size_t)(blockIdx.x * 8 + g) * 64;
    M[mrow + c]      = ms;
    M[mrow + 32 + c] = mc;
    acc2d[g][c]      = ms * ms;
    acc2d[g][32 + c] = mc * mc;
    __syncthreads();
    if (tid < 64) {
        float s = 0.0f;
        #pragma unroll
        for (int gg = 0; gg < 8; ++gg) s += acc2d[gg][tid];
        const int geo = blockIdx.x * 8;            // first g of block
        const int b  = geo >> 11;
        const int gb = (geo >> 7) & 15;
        atomicAdd(&part2[(b * 16 + gb) * 64 + tid], s);
    }
}

// ---------------- K3f: finalize (sums part2 over gb) ----------------
__global__ __launch_bounds__(256) void k3_final(const float* __restrict__ M,
                                                const float* __restrict__ lc,
                                                const float* __restrict__ part2,
                                                float* __restrict__ out)
{
    __shared__ float mt[64][65];
    __shared__ float lt[64][65];
    __shared__ float ir[64];
    __shared__ float iln[64];
    int tid = threadIdx.x;
    int b  = blockIdx.x >> 5;
    int g0 = (blockIdx.x & 31) * 64;
    if (tid < 64) {
        float s = 0.0f;
        #pragma unroll
        for (int gb = 0; gb < 16; ++gb) s += part2[(b * 16 + gb) * 64 + tid];
        ir[tid] = 1.0f / sqrtf(s);
    }
    const float* Mb = M  + ((size_t)(b * Gg + g0)) * 64;
    const float* Lb = lc + ((size_t)(b * Gg + g0)) * 64;
    #pragma unroll
    for (int i = 0; i < 4; ++i) {
        int f = i * 1024 + tid * 4;
        int r = f >> 6, col = f & 63;
        float4 mv = *(const float4*)(Mb + f);
        float4 lv = *(const float4*)(Lb + f);
        mt[r][col] = mv.x; mt[r][col+1] = mv.y; mt[r][col+2] = mv.z; mt[r][col+3] = mv.w;
        lt[r][col] = lv.x; lt[r][col+1] = lv.y; lt[r][col+2] = lv.z; lt[r][col+3] = lv.w;
    }
    __syncthreads();
    if (tid < 64) {
        float ss = 0.0f;
        #pragma unroll
        for (int c = 0; c < 64; ++c) { float v = lt[tid][c]; ss = fmaf(v, v, ss); }
        iln[tid] = 1.0f / sqrtf(ss);
    }
    __syncthreads();
    int gl = tid & 63;
    int c0 = tid >> 6;
    float il = iln[gl];
    int obase = (b * 128) * Gg + g0 + gl;
    #pragma unroll
    for (int i = 0; i < 16; ++i) {
        int c = c0 + i * 4;
        float lcl = lt[gl][c] * il;
        float x = mt[gl][c] * ir[c];
        float kl = 0.5f * x * (1.0f + erff(x * 0.70710678118654752f));
        out[obase + c * Gg]        = kl - lcl;   // line_element
        out[obase + (c + 64) * Gg] = lcl;        // lc_line
    }
}

extern "C" void kernel_launch(void* const* d_in, const int* in_sizes, int n_in,
                              void* d_out, int out_size, void* d_ws, size_t ws_size,
                              hipStream_t stream)
{
    (void)in_sizes; (void)n_in; (void)out_size; (void)ws_size;
    const float* lc  = (const float*)d_in[0];   // (8,2048,64)
    const float* knn = (const float*)d_in[1];   // (8,2048,32,64)
    const float* fB  = (const float*)d_in[2];   // (68,32)
    float* out = (float*)d_out;                 // (8,128,2048) f32
    char* ws = (char*)d_ws;
    double* part  = (double*)(ws + PART_OFF);
    float*  part2 = (float*)(ws + PART_OFF);    // reused after k1_final
    float*  stdp  = (float*)(ws + STD_OFF);
    float*  M     = (float*)(ws + M_OFF);
    float*  A     = (float*)(ws + ACC_OFF);

    hipLaunchKernelGGL(k2a_main, dim3(1024), dim3(256), 0, stream,
                       knn, lc, fB, part, A);
    hipLaunchKernelGGL(k1_final, dim3(1), dim3(256), 0, stream, part, stdp);
    (void)hipMemsetAsync(part2, 0, 128 * 64 * sizeof(float), stream);
    hipLaunchKernelGGL(k2bp_main, dim3(2048), dim3(256), 0, stream,
                       A, stdp, M, part2);
    hipLaunchKernelGGL(k3_final, dim3(256), dim3(256), 0, stream, M, lc, part2, out);
}

// Round 27
// 81.787 us; speedup vs baseline: 1.7091x; 1.0235x over previous
//
#include <hip/hip_runtime.h>
#include <math.h>

// B=8, G=2048, K=32, N=64.
// Algebraic: k_anp_x = mean(ff,K) exactly (e_x cancels); std/p/nrm branch
// dead; norm over G cancels the 2. Projection linear in 1/std => matmul on
// RAW diffs; inv applied after the global std is known. knn read ONCE.
//
//  k2a : persistent pipeline, 64-row tiles, 34.5KB LDS, 4 blocks/CU.
//        KEY (R27): P1 wave w writes rows 16w..16w+15 and P2 wave w reads
//        the SAME rows -> the per-tile __syncthreads protected nothing.
//        Removed: each wave free-runs its own LOAD->COMPUTE->MATMUL pipeline
//        (in-order wave + compiler lgkmcnt fences the ds_write->ds_read).
//        One barrier remains before the s/s2 tree (elds4 aliasing).
//  k1f : std from 1024 block partials
//  k2bp: inv + sincos + K-reduce -> M, fused ssq partial (atomicAdd)
//  k3f : finalize (sums part2 over gb, gelu, output)

constexpr int Gg = 2048;

typedef float v2f __attribute__((ext_vector_type(2)));

constexpr size_t PART_OFF = 0;       // k2a: 1024*2 dbl (16KB); later part2 (32KB)
constexpr size_t STD_OFF  = 32768;   // 1 float
constexpr size_t M_OFF    = 65536;   // 4 MiB
constexpr size_t ACC_OFF  = 65536 + 4194304;   // 32 MB raw acc

// ---------------- K2a: persistent per-wave-pipelined fused kernel ----------------
__global__ __launch_bounds__(256, 4) void k2a_main(const float* __restrict__ knn,
                                                   const float* __restrict__ lc,
                                                   const float* __restrict__ fB,
                                                   double* __restrict__ part,
                                                   float* __restrict__ A)
{
    __shared__ float4 elds4[2][17][65];    // 34.5 KB double buffer (pad 65)

    const int tid = threadIdx.x;
    const int l   = tid & 63;
    const int w   = tid >> 6;
    // phase-1 ids (4 threads per row); wave w covers rows 16w..16w+15
    const int p1row = tid >> 2;            // 0..63 (tile-local)
    const int sub   = tid & 3;
    const int p1g   = p1row >> 5;          // 0..1 (tile-local g)
    // phase-2 ids: wave w rows w*16 + lh*8 .. +8  (same rows as its P1!)
    const int c     = l & 31;
    const int lh    = l >> 5;
    const int rbp2  = w * 16 + lh * 8;     // tile-local row base

    const size_t blk = blockIdx.x;         // block covers rows blk*512..+511

    // fB column pairs
    v2f fbr2[34];
    #pragma unroll
    for (int j = 0; j < 34; ++j)
        fbr2[j] = (v2f){fB[(2 * j) * 32 + c], fB[(2 * j + 1) * 32 + c]};

    double sD = 0.0, s2D = 0.0;

    auto P1 = [&](int t, int bsel) {
        const float4* rowp = (const float4*)knn
            + ((size_t)blk * 512 + t * 64 + p1row) * 16 + sub * 4;
        const float4* lcp  = (const float4*)lc
            + ((size_t)blk * 16 + t * 2 + p1g) * 16 + sub * 4;
        float dotp = 0.0f;
        float kn0 = 0, kn1 = 0, kn2 = 0, ln0 = 0, ln1 = 0, ln2 = 0;
        float s0 = 0.f, s1 = 0.f, s2c = 0.f, s3 = 0.f;
        float q0 = 0.f, q1 = 0.f, q2c = 0.f, q3 = 0.f;
        #pragma unroll
        for (int j = 0; j < 4; ++j) {
            float4 qv = rowp[j];
            float4 lv = lcp[j];
            float e0 = qv.x - lv.x, e1 = qv.y - lv.y;
            float e2 = qv.z - lv.z, e3 = qv.w - lv.w;
            if (j == 0 && sub == 0) {
                kn0 = e0; kn1 = e1; kn2 = e2;
                ln0 = lv.x; ln1 = lv.y; ln2 = lv.z;
            }
            dotp = fmaf(e0, lv.x, dotp); dotp = fmaf(e1, lv.y, dotp);
            dotp = fmaf(e2, lv.z, dotp); dotp = fmaf(e3, lv.w, dotp);
            s0 += e0; s1 += e1; s2c += e2; s3 += e3;
            q0 = fmaf(e0, e0, q0); q1 = fmaf(e1, e1, q1);
            q2c = fmaf(e2, e2, q2c); q3 = fmaf(e3, e3, q3);
            elds4[bsel][sub * 4 + j][p1row] = make_float4(e0, e1, e2, e3);
        }
        float d1  = dotp + __shfl_xor(dotp, 1);
        float dot = d1 + __shfl_xor(d1, 2);
        if (sub == 0) {
            float a0 = kn0, a1 = kn1, a2 = kn2;
            float b0 = ln0, b1 = ln1, b2 = ln2;
            float t2;
            if (a0 < a1) { t2 = a0; a0 = a1; a1 = t2; }
            if (a1 < a2) { t2 = a1; a1 = a2; a2 = t2; }
            if (a0 < a1) { t2 = a0; a0 = a1; a1 = t2; }
            if (b0 < b1) { t2 = b0; b0 = b1; b1 = t2; }
            if (b1 < b2) { t2 = b1; b1 = b2; b2 = t2; }
            if (b0 < b1) { t2 = b0; b0 = b1; b1 = t2; }
            float cr0 = a1 * b2 - a2 * b1;
            float cr1 = a2 * b0 - a0 * b2;
            float cr2 = a0 * b1 - a1 * b0;
            elds4[bsel][16][p1row] = make_float4(cr0, cr1, cr2, dot);
        }
        sD  += (double)s0 + (double)s1 + (double)s2c + (double)s3;
        s2D += (double)q0 + (double)q1 + (double)q2c + (double)q3;
    };

    auto P2 = [&](int t, int bsel) {
        float* Ab = A + ((size_t)blk * 512 + t * 64 + rbp2) * 32 + c;
        __builtin_amdgcn_s_setprio(1);
        #pragma unroll
        for (int jj = 0; jj < 4; ++jj) {
            const int r0 = rbp2 + 2 * jj;
            const int r1 = r0 + 1;
            v2f aA0 = (v2f){0.f, 0.f}, aA1 = (v2f){0.f, 0.f};
            v2f aB0 = (v2f){0.f, 0.f}, aB1 = (v2f){0.f, 0.f};
            #pragma unroll
            for (int kq = 0; kq < 17; ++kq) {
                float4 eA = elds4[bsel][kq][r0];
                float4 eB = elds4[bsel][kq][r1];
                aA0 = __builtin_elementwise_fma((v2f){eA.x, eA.y}, fbr2[2 * kq],     aA0);
                aA1 = __builtin_elementwise_fma((v2f){eA.z, eA.w}, fbr2[2 * kq + 1], aA1);
                aB0 = __builtin_elementwise_fma((v2f){eB.x, eB.y}, fbr2[2 * kq],     aB0);
                aB1 = __builtin_elementwise_fma((v2f){eB.z, eB.w}, fbr2[2 * kq + 1], aB1);
            }
            Ab[(size_t)(2 * jj) * 32]     = (aA0.x + aA0.y) + (aA1.x + aA1.y);
            Ab[(size_t)(2 * jj + 1) * 32] = (aB0.x + aB0.y) + (aB1.x + aB1.y);
        }
        __builtin_amdgcn_s_setprio(0);
    };

    // per-wave free-running pipeline: NO per-tile barriers
    P1(0, 0);
    for (int t = 0; t < 8; ++t) {
        if (t < 7) P1(t + 1, (t + 1) & 1);   // loads fly during P2(t)
        P2(t, t & 1);
    }

    // one barrier: all waves done with elds4 before aliasing it as shd
    __syncthreads();
    double* shd = (double*)&elds4[0][0][0];
    shd[tid] = sD; shd[256 + tid] = s2D;
    __syncthreads();
    for (int off = 128; off > 0; off >>= 1) {
        if (tid < off) { shd[tid] += shd[tid + off]; shd[256 + tid] += shd[256 + tid + off]; }
        __syncthreads();
    }
    if (tid == 0) { part[blk * 2] = shd[0]; part[blk * 2 + 1] = shd[256]; }
}

// ---------------- K1f: std from 1024 partials ----------------
__global__ __launch_bounds__(256) void k1_final(const double* __restrict__ part,
                                                float* __restrict__ stdp)
{
    int tid = threadIdx.x;
    double s = 0.0, s2 = 0.0;
    for (int i = tid; i < 1024; i += 256) { s += part[2*i]; s2 += part[2*i+1]; }
    __shared__ double sh[512];
    sh[tid] = s; sh[256 + tid] = s2;
    __syncthreads();
    for (int off = 128; off > 0; off >>= 1) {
        if (tid < off) { sh[tid] += sh[tid + off]; sh[256 + tid] += sh[256 + tid + off]; }
        __syncthreads();
    }
    if (tid == 0) {
        double S = sh[0], S2 = sh[256];
        double Mn = 33554432.0;
        double var = (S2 - S * S / Mn) / (Mn - 1.0);
        stdp[0] = (float)sqrt(var);
    }
}

// ---------------- K2bp: inv+sincos+K-reduce -> M, + ssq partial ----------------
__global__ __launch_bounds__(256) void k2bp_main(const float* __restrict__ A,
                                                 const float* __restrict__ stdp,
                                                 float* __restrict__ M,
                                                 float* __restrict__ part2)
{
    __shared__ float acc2d[8][64];
    const int tid = threadIdx.x;
    const int g   = tid >> 5;           // 0..7
    const int c   = tid & 31;
    const float inv = 1.0f / (stdp[0] + 1e-5f);
    const float* Ab = A + ((size_t)blockIdx.x * 256 + g * 32) * 32 + c;
    float ssum = 0.0f, csum = 0.0f;
    #pragma unroll 4
    for (int k = 0; k < 32; ++k) {
        float p  = Ab[(size_t)k * 32] * inv;   // revolutions
        float rv = p - rintf(p);               // exact reduction
        ssum += __builtin_amdgcn_sinf(rv);
        csum += __builtin_amdgcn_cosf(rv);
    }
    float ms = ssum * (1.0f / 32.0f);
    float mc = csum * (1.0f / 32.0f);
    const size_t mrow = (size_t)(blockIdx.x * 8 + g) * 64;
    M[mrow + c]      = ms;
    M[mrow + 32 + c] = mc;
    acc2d[g][c]      = ms * ms;
    acc2d[g][32 + c] = mc * mc;
    __syncthreads();
    if (tid < 64) {
        float s = 0.0f;
        #pragma unroll
        for (int gg = 0; gg < 8; ++gg) s += acc2d[gg][tid];
        const int geo = blockIdx.x * 8;            // first g of block
        const int b  = geo >> 11;
        const int gb = (geo >> 7) & 15;
        atomicAdd(&part2[(b * 16 + gb) * 64 + tid], s);
    }
}

// ---------------- K3f: finalize (sums part2 over gb) ----------------
__global__ __launch_bounds__(256) void k3_final(const float* __restrict__ M,
                                                const float* __restrict__ lc,
                                                const float* __restrict__ part2,
                                                float* __restrict__ out)
{
    __shared__ float mt[64][65];
    __shared__ float lt[64][65];
    __shared__ float ir[64];
    __shared__ float iln[64];
    int tid = threadIdx.x;
    int b  = blockIdx.x >> 5;
    int g0 = (blockIdx.x & 31) * 64;
    if (tid < 64) {
        float s = 0.0f;
        #pragma unroll
        for (int gb = 0; gb < 16; ++gb) s += part2[(b * 16 + gb) * 64 + tid];
        ir[tid] = 1.0f / sqrtf(s);
    }
    const float* Mb = M  + ((size_t)(b * Gg + g0)) * 64;
    const float* Lb = lc + ((size_t)(b * Gg + g0)) * 64;
    #pragma unroll
    for (int i = 0; i < 4; ++i) {
        int f = i * 1024 + tid * 4;
        int r = f >> 6, col = f & 63;
        float4 mv = *(const float4*)(Mb + f);
        float4 lv = *(const float4*)(Lb + f);
        mt[r][col] = mv.x; mt[r][col+1] = mv.y; mt[r][col+2] = mv.z; mt[r][col+3] = mv.w;
        lt[r][col] = lv.x; lt[r][col+1] = lv.y; lt[r][col+2] = lv.z; lt[r][col+3] = lv.w;
    }
    __syncthreads();
    if (tid < 64) {
        float ss = 0.0f;
        #pragma unroll
        for (int c = 0; c < 64; ++c) { float v = lt[tid][c]; ss = fmaf(v, v, ss); }
        iln[tid] = 1.0f / sqrtf(ss);
    }
    __syncthreads();
    int gl = tid & 63;
    int c0 = tid >> 6;
    float il = iln[gl];
    int obase = (b * 128) * Gg + g0 + gl;
    #pragma unroll
    for (int i = 0; i < 16; ++i) {
        int c = c0 + i * 4;
        float lcl = lt[gl][c] * il;
        float x = mt[gl][c] * ir[c];
        float kl = 0.5f * x * (1.0f + erff(x * 0.70710678118654752f));
        out[obase + c * Gg]        = kl - lcl;   // line_element
        out[obase + (c + 64) * Gg] = lcl;        // lc_line
    }
}

extern "C" void kernel_launch(void* const* d_in, const int* in_sizes, int n_in,
                              void* d_out, int out_size, void* d_ws, size_t ws_size,
                              hipStream_t stream)
{
    (void)in_sizes; (void)n_in; (void)out_size; (void)ws_size;
    const float* lc  = (const float*)d_in[0];   // (8,2048,64)
    const float* knn = (const float*)d_in[1];   // (8,2048,32,64)
    const float* fB  = (const float*)d_in[2];   // (68,32)
    float* out = (float*)d_out;                 // (8,128,2048) f32
    char* ws = (char*)d_ws;
    double* part  = (double*)(ws + PART_OFF);
    float*  part2 = (float*)(ws + PART_OFF);    // reused after k1_final
    float*  stdp  = (float*)(ws + STD_OFF);
    float*  M     = (float*)(ws + M_OFF);
    float*  A     = (float*)(ws + ACC_OFF);

    hipLaunchKernelGGL(k2a_main, dim3(1024), dim3(256), 0, stream,
                       knn, lc, fB, part, A);
    hipLaunchKernelGGL(k1_final, dim3(1), dim3(256), 0, stream, part, stdp);
    (void)hipMemsetAsync(part2, 0, 128 * 64 * sizeof(float), stream);
    hipLaunchKernelGGL(k2bp_main, dim3(2048), dim3(256), 0, stream,
                       A, stdp, M, part2);
    hipLaunchKernelGGL(k3_final, dim3(256), dim3(256), 0, stream, M, lc, part2, out);
}